// Round 8
// baseline (35.016 us; speedup 1.0000x reference)
//
#include <hip/hip_runtime.h>
#include <math.h>

#define DIM   100
#define NV    64
#define BS    512
#define MAXCH 1792   // multiple of 128; >= 128 combos * 13 chunks max

// ---------------------------------------------------------------------------
// One block per (batch, direction m). Mask as u8 in LDS (10 KB). Ref keeps
// exactly one sample per integer u-cell crossed; per combo we binary-search
// the exact last valid step T (bit-identical float exprs), K = cells crossed,
// and enumerate kept samples k=0..K directly: t = ceil((D+k)*B - 5e-3) with
// a one-step fixup against the bit-exact floor(u(t)) (error budget ~1e-4 on
// iou, threshold 2.26e-3). Work pool = 8-kept-sample chunks; each 8-lane
// sub-group pulls FOUR consecutive entries with one ds_read_b64 -> 4
// independent sample chains per lane (ILP x4). Sentinel entries (c=0,k=15)
// fail kf<=Kf -> weight 0; t clamped, indices clamped -> garbage-proof.
// AX is block-uniform -> compile-time template (no per-sample selects).
// LDS ~17.7 KB -> 8 blocks/CU; 2048-block grid fully co-resident.
// ---------------------------------------------------------------------------
template<bool AX>
__device__ __forceinline__ float mainloop(
    const unsigned char* smask, const float (*prm)[8],
    const unsigned short* chunkTab, int totE, int tid) {
  const int grp = tid >> 5;                // 0..7
  const int sub = (tid >> 3) & 3;          // 0..3
  const int st  = tid & 7;                 // kept-sample index within chunk
  const int base0 = grp * 16 + sub * 4;
  float acc = 0.0f;

  for (int i = 0; i * 128 < totE; ++i) {
    const ushort4 ent = *reinterpret_cast<const ushort4*>(
        &chunkTab[i * 128 + base0]);       // ds_read_b64, 8B aligned

    #define SAMPLE(e) {                                                    \
      const int c = (e) >> 4;                                              \
      const float kf = (float)((((e) & 15) << 3) | st);                    \
      const float4 p = *reinterpret_cast<const float4*>(&prm[c][0]);       \
      const float4 q = *reinterpret_cast<const float4*>(&prm[c][4]);       \
      const float vu = AX ? p.z : p.w;                                     \
      const float u0 = AX ? p.x : p.y;                                     \
      const float fu0 = floorf(u0);                                        \
      const float ck = fu0 + ((vu > 0.0f) ? kf : -kf);                     \
      const float te = ceilf(fmaf(kf, q.z, q.w) - 0.005f);                 \
      const float u1 = __fadd_rn(__fmul_rn(te, vu), u0);                   \
      float t = (floorf(u1) == ck) ? te : (te + 1.0f);                     \
      t = fminf(fmaxf(t, 0.0f), 300.0f);                                   \
      const float xs = __fadd_rn(__fmul_rn(t, p.z), p.x);                  \
      const float ys = __fadd_rn(__fmul_rn(t, p.w), p.y);                  \
      const float X0 = floorf(xs), Y0 = floorf(ys);                        \
      const float wx1 = xs - X0, wy1 = ys - Y0;                            \
      const float wx0 = 1.0f - wx1, wy0 = 1.0f - wy1;                      \
      const int ix0 = (int)X0, iy0 = (int)Y0;                              \
      const int xi0 = min(max(ix0, 0), DIM - 1);                           \
      const int xi1 = min(max(ix0 + 1, 0), DIM - 1);                       \
      const int yi0 = min(max(iy0, 0), DIM - 1);                           \
      const int yi1 = min(max(iy0 + 1, 0), DIM - 1);                       \
      const int a00 = yi0 * DIM + xi0, a01 = yi1 * DIM + xi0;              \
      const int xoff = xi1 - xi0;                                          \
      const float g00 = (float)smask[a00];                                 \
      const float g01 = (float)smask[a01];                                 \
      const float g10 = (float)smask[a00 + xoff];                          \
      const float g11 = (float)smask[a01 + xoff];                          \
      const float val = wx0 * (wy0 * g00 + wy1 * g01) +                    \
                        wx1 * (wy0 * g10 + wy1 * g11);                     \
      const float w = (kf <= q.y) ? q.x : 0.0f;                            \
      acc = fmaf(w, val, acc);                                             \
    }
    SAMPLE(ent.x); SAMPLE(ent.y); SAMPLE(ent.z); SAMPLE(ent.w);
    #undef SAMPLE
  }
  return acc;
}

__global__ __launch_bounds__(256, 8) void diffiou_intersect(
    const float* __restrict__ poly, const float* __restrict__ gt_mask,
    float* __restrict__ ws) {
  __shared__ unsigned char smask[DIM * DIM];     // 10000 B
  __shared__ float prm[128][8];                  // 4096 B: x0,y0,vx,vy,shw,Kf,B,A
  __shared__ unsigned short chunkTab[MAXCH];     // 3584 B
  __shared__ int   wsum[2];
  __shared__ int   totalChunks;
  __shared__ float red[4];

  const int bid = blockIdx.x;
  const int b   = bid >> 2;
  const int m   = bid & 3;
  const bool ax = (m < 2);                 // DIRECTIONS = x,x,y,y
  const int tid = threadIdx.x;

  // ---- phase 1: stage mask (fp32 -> u8), prefill sentinel table ----
  {
    const float4* src = reinterpret_cast<const float4*>(
        gt_mask + (size_t)(b * 4 + m) * (DIM * DIM));
    for (int j = tid; j < DIM * DIM / 4; j += 256) {
      const float4 v = src[j];
      uchar4 c;
      c.x = (unsigned char)__float2int_rn(v.x * 255.0f);
      c.y = (unsigned char)__float2int_rn(v.y * 255.0f);
      c.z = (unsigned char)__float2int_rn(v.z * 255.0f);
      c.w = (unsigned char)__float2int_rn(v.w * 255.0f);
      *reinterpret_cast<uchar4*>(&smask[j * 4]) = c;
    }
    for (int j = tid; j < MAXCH; j += 256) chunkTab[j] = 15;  // c=0,k=15 sentinel
  }

  // ---- per-combo setup ----
  int ncv = 0;
  if (tid < 128) {
    const int e  = tid >> 1;
    const int fb = tid & 1;
    const float* pb = poly + (size_t)b * NV * 2;
    const float ex0 = pb[e * 2 + 0], ey0 = pb[e * 2 + 1];
    const int   en  = (e + 1) & (NV - 1);
    const float ex1 = pb[en * 2 + 0], ey1 = pb[en * 2 + 1];
    const float sign = (ax ? (ex1 > ex0) : (ey1 > ey0)) ? 1.0f : -1.0f;
    const float x0 = fb ? ex1 : ex0, y0 = fb ? ey1 : ey0;
    const float x1 = fb ? ex0 : ex1, y1 = fb ? ey0 : ey1;
    float vx = (x1 - x0) + 1e-6f;
    float vy = (y1 - y0) + 1e-6f;
    const float n = __fsqrt_rn(__fadd_rn(__fmul_rn(vx, vx), __fmul_rn(vy, vy)));
    vx = __fdiv_rn(vx, n);
    vy = __fdiv_rn(vy, n);
    // bbox + tolerances; u-bound [0,99] folded into the axis coord (exact)
    float xlo = fminf(x0, x1) - 0.001f, xhi = fmaxf(x0, x1) + 0.001f;
    float ylo = fminf(y0, y1) - 0.001f, yhi = fmaxf(y0, y1) + 0.001f;
    if (ax) { xlo = fmaxf(xlo, 0.0f); xhi = fminf(xhi, (float)(DIM - 1)); }
    else    { ylo = fmaxf(ylo, 0.0f); yhi = fminf(yhi, (float)(DIM - 1)); }

    #define VALID_AT(tt, out) {                                   \
      const float tf_ = (float)(tt);                              \
      const float xs_ = __fadd_rn(__fmul_rn(tf_, vx), x0);        \
      const float ys_ = __fadd_rn(__fmul_rn(tf_, vy), y0);        \
      out = (xs_ <= xhi) && (xs_ >= xlo) &&                       \
            (ys_ <= yhi) && (ys_ >= ylo);                         \
    }
    int T;
    bool v200; VALID_AT(200, v200);
    if (v200) { T = 200; }
    else {
      int lo = 0, hi = 200;
      #pragma unroll
      for (int it = 0; it < 8; ++it) {
        const int mid = (lo + hi) >> 1;
        bool vm; VALID_AT(mid, vm);
        if (vm) lo = mid; else hi = mid;
      }
      T = lo;
    }
    #undef VALID_AT

    // kept-sample machinery
    const float vu  = ax ? vx : vy;
    const float u0  = ax ? x0 : y0;
    const float fu0 = floorf(u0);
    const float uT  = __fadd_rn(__fmul_rn((float)T, vu), u0);
    int K = abs((int)floorf(uT) - (int)fu0);
    K = min(K, 99);
    const float B = __fdiv_rn(1.0f, fabsf(vu));
    const float D = (vu > 0.0f) ? (fu0 - u0) : (u0 - fu0 - 1.0f);
    prm[tid][0] = x0;  prm[tid][1] = y0;
    prm[tid][2] = vx;  prm[tid][3] = vy;
    prm[tid][4] = sign * (0.5f / 255.0f);
    prm[tid][5] = (float)K;
    prm[tid][6] = B;
    prm[tid][7] = D * B;                   // A
    ncv = (K >> 3) + 1;                    // 8-kept chunks, <= 13
  }

  // ---- prefix scan (2 waves) + scatter chunk table ----
  int v = ncv;
  #pragma unroll
  for (int i = 1; i < 64; i <<= 1) {
    const int w = __shfl_up(v, i, 64);
    if ((tid & 63) >= i) v += w;
  }
  if (((tid & 63) == 63) && (tid < 128)) wsum[tid >> 6] = v;
  __syncthreads();
  if ((tid >= 64) && (tid < 128)) v += wsum[0];
  if (tid < 128) {
    const int start = v - ncv;
    for (int k = 0; k < ncv; ++k)
      chunkTab[start + k] = (unsigned short)((tid << 4) | k);
    if (tid == 127) totalChunks = v;
  }
  __syncthreads();

  const int totE = totalChunks;
  const float acc = ax ? mainloop<true >(smask, prm, chunkTab, totE, tid)
                       : mainloop<false>(smask, prm, chunkTab, totE, tid);

  // ---- block reduce (4 waves) ----
  float a = acc;
  #pragma unroll
  for (int o = 32; o > 0; o >>= 1) a += __shfl_xor(a, o, 64);
  if ((tid & 63) == 0) red[tid >> 6] = a;
  __syncthreads();
  if (tid == 0) {
    const float s = red[0] + red[1] + red[2] + red[3];
    ws[bid] = fabsf(s);
  }
}

// ---------------------------------------------------------------------------
// Kernel 2: per-batch areas + final IoU. One wave per batch.
// ---------------------------------------------------------------------------
__device__ __forceinline__ float wave_area(const float* P, int b, int v) {
  const float x0 = P[(size_t)(b * NV + v) * 2 + 0];
  const float y0 = P[(size_t)(b * NV + v) * 2 + 1];
  const int vn = (v + 1) & (NV - 1);
  const float x1 = P[(size_t)(b * NV + vn) * 2 + 0];
  const float y1 = P[(size_t)(b * NV + vn) * 2 + 1];
  float ym = y0;
  #pragma unroll
  for (int o = 32; o > 0; o >>= 1) ym = fmaxf(ym, __shfl_xor(ym, o, 64));
  float term = (x1 - x0) * (ym - (y1 + y0) * 0.5f);
  #pragma unroll
  for (int o = 32; o > 0; o >>= 1) term += __shfl_xor(term, o, 64);
  return fabsf(term);
}

__global__ __launch_bounds__(64) void diffiou_finalize(
    const float* __restrict__ poly, const float* __restrict__ gt,
    const float* __restrict__ ws, float* __restrict__ out) {
  const int b = blockIdx.x;
  const int v = threadIdx.x;
  const float pa = wave_area(poly, b, v);
  const float ga = wave_area(gt, b, v);
  if (v == 0) {
    const float ia = 0.25f * (ws[b * 4 + 0] + ws[b * 4 + 1] +
                              ws[b * 4 + 2] + ws[b * 4 + 3]);
    out[b] = ia / (pa + ga - ia);
  }
}

// ---------------------------------------------------------------------------
extern "C" void kernel_launch(void* const* d_in, const int* in_sizes, int n_in,
                              void* d_out, int out_size, void* d_ws, size_t ws_size,
                              hipStream_t stream) {
  const float* poly    = (const float*)d_in[0];
  const float* gt      = (const float*)d_in[1];
  const float* gt_mask = (const float*)d_in[2];
  float* out = (float*)d_out;
  float* ws  = (float*)d_ws;   // 2048 floats: |s| per (batch, direction)

  hipLaunchKernelGGL(diffiou_intersect, dim3(BS * 4), dim3(256), 0, stream,
                     poly, gt_mask, ws);
  hipLaunchKernelGGL(diffiou_finalize, dim3(BS), dim3(64), 0, stream,
                     poly, gt, ws, out);
}